// Round 7
// baseline (745.600 us; speedup 1.0000x reference)
//
#include <hip/hip_runtime.h>
#include <hip/hip_bf16.h>

// Problem constants (reference: T,H,I,E,K = 4096,1024,2048,32,4)
#define T_TOK 4096
#define H_DIM 1024
#define I_DIM 2048
#define N_EXP 32
#define TOPK  4
#define TKTOT (T_TOK * TOPK)      // 16384 expert-row slots
#define ROWS_MAX 24576            // 4096 shared rows + <=20480 padded expert rows
#define MAX_TILES 192             // 32 shared tiles + <=159 expert tiles
#define BM 128
#define BK 64
#define LDB 72                    // BK + 8 f16 pad -> 144 B rows (16B-aligned)

typedef _Float16 f16;
typedef __attribute__((ext_vector_type(2))) f16  f16x2;
typedef __attribute__((ext_vector_type(4))) f16  f16x4;
typedef __attribute__((ext_vector_type(8))) f16  f16x8;
typedef __attribute__((ext_vector_type(4))) float f32x4;

// async global->LDS, 16B per lane; LDS dest is wave-uniform base + lane*16
__device__ __forceinline__ void glds16(const f16* g, f16* l) {
  __builtin_amdgcn_global_load_lds(
      (const __attribute__((address_space(1))) void*)g,
      (__attribute__((address_space(3))) void*)l, 16, 0, 0);
}

// ---------------------------------------------------------------- prep ----
__global__ void prep_kernel(const float* __restrict__ x, f16* __restrict__ xb,
                            int* __restrict__ row_token,
                            int* __restrict__ counts) {
  int gid = blockIdx.x * blockDim.x + threadIdx.x;   // 0 .. T*H/4-1
  float4 v = *(const float4*)(x + (size_t)gid * 4);
  f16x4 hv = { (f16)v.x, (f16)v.y, (f16)v.z, (f16)v.w };
  *(f16x4*)(xb + (size_t)gid * 4) = hv;
  if (gid < ROWS_MAX) row_token[gid] = (gid < T_TOK) ? gid : 0;
  if (gid < N_EXP) counts[gid] = 0;
}

// -------------------------------------------------------------- router ----
__global__ void router_kernel(const float* __restrict__ x,
                              const float* __restrict__ rw,
                              int* __restrict__ expert_sel,
                              float* __restrict__ weight_sel,
                              int* __restrict__ counts) {
  int wid = threadIdx.x >> 6, lane = threadIdx.x & 63;
  int t = blockIdx.x * 4 + wid;
  float xr[16];
#pragma unroll
  for (int j = 0; j < 16; ++j) xr[j] = x[(size_t)t * H_DIM + lane + j * 64];
  float l[32];
#pragma unroll
  for (int e = 0; e < 32; ++e) {
    float p = 0.f;
#pragma unroll
    for (int j = 0; j < 16; ++j) p += xr[j] * rw[(size_t)e * H_DIM + lane + j * 64];
#pragma unroll
    for (int off = 32; off; off >>= 1) p += __shfl_xor(p, off, 64);
    l[e] = p;
  }
  if (lane == 0) {
    unsigned used = 0;
    int sel[4]; float lv[4];
#pragma unroll
    for (int k = 0; k < 4; ++k) {
      float bv = -3.4e38f; int bi = 0;
#pragma unroll
      for (int e = 0; e < 32; ++e) {
        bool better = (((used >> e) & 1u) == 0u) && (l[e] > bv);
        bv = better ? l[e] : bv;
        bi = better ? e : bi;
      }
      used |= 1u << bi; sel[k] = bi; lv[k] = bv;
    }
    float m = lv[0];
    float p0 = __expf(lv[0] - m), p1 = __expf(lv[1] - m);
    float p2 = __expf(lv[2] - m), p3 = __expf(lv[3] - m);
    float s = p0 + p1 + p2 + p3;
    float wv[4] = { p0 / s, p1 / s, p2 / s, p3 / s };
#pragma unroll
    for (int k = 0; k < 4; ++k) {
      expert_sel[t * 4 + k] = sel[k];
      weight_sel[t * 4 + k] = wv[k];
      atomicAdd(&counts[sel[k]], 1);
    }
  }
}

// ---------------------------------------------------------------- scan ----
__global__ void scan_kernel(const int* __restrict__ counts, int* __restrict__ cursor,
                            int* __restrict__ tile_expert, int* __restrict__ tile_row0,
                            int* __restrict__ ntiles) {
  if (threadIdx.x != 0 || blockIdx.x != 0) return;
  int nt = 0;
  for (int i = 0; i < T_TOK / BM; ++i) { tile_expert[nt] = N_EXP; tile_row0[nt] = i * BM; ++nt; }
  int pos = T_TOK;
  for (int e = 0; e < N_EXP; ++e) {
    cursor[e] = pos;
    int c = counts[e];
    int nte = (c + BM - 1) / BM;
    for (int i = 0; i < nte; ++i) { tile_expert[nt] = e; tile_row0[nt] = pos + i * BM; ++nt; }
    pos += nte * BM;
  }
  ntiles[0] = nt;
}

// ------------------------------------------------------------- scatter ----
__global__ void scatter_kernel(const int* __restrict__ expert_sel,
                               const float* __restrict__ weight_sel,
                               int* __restrict__ cursor,
                               int* __restrict__ row_token,
                               int* __restrict__ slot_of) {
  int i = blockIdx.x * blockDim.x + threadIdx.x;
  if (i >= TKTOT) return;
  int e = expert_sel[i];
  int pos = atomicAdd(&cursor[e], 1);
  row_token[pos] = i >> 2;
  slot_of[i] = pos;
  (void)weight_sel;
}

// ------------------------- B staging helpers (fetch regs / cvt+write LDS) --
// thread covers 2 n x 8 k via float2 rows (BN=64 staging).
struct Bf2 { float2 g[8]; };
__device__ __forceinline__ Bf2 fetch_b2(const float* __restrict__ src, size_t ldn) {
  Bf2 r;
#pragma unroll
  for (int j = 0; j < 8; ++j) r.g[j] = *(const float2*)(src + (size_t)j * ldn);
  return r;
}
__device__ __forceinline__ void write_b2(const Bf2& b,
                                         f16 (*__restrict__ Bs)[LDB], int nq, int kr) {
  const float* ga = (const float*)b.g;        // ga[j*2 + comp]
  int ks = (8 * kr) ^ ((nq & 7) << 3);        // swizzled 16B slot (f16 units)
#pragma unroll
  for (int i = 0; i < 2; ++i) {
    union { f16x2 p[4]; f16x8 v; } u;
#pragma unroll
    for (int j = 0; j < 4; ++j)
      u.p[j] = __builtin_bit_cast(
          f16x2, __builtin_amdgcn_cvt_pkrtz(ga[(2 * j) * 2 + i],
                                            ga[(2 * j + 1) * 2 + i]));
    *(f16x8*)&Bs[2 * nq + i][ks] = u.v;
  }
}
// read-side mirror: write row = 2*nq+i -> key (row>>1)&7
__device__ __forceinline__ int rswz1(int row, int kf16) {
  return kf16 ^ (((row >> 1) & 7) << 3);
}

// ---------------------------------------------------------------- GEMM1 ---
// 128x64 tile of gate AND up. A via global_load_lds (dbuf, source-swizzled),
// B reg-staged fp32->f16. 4 waves; acc 4x2 per matrix.
__global__ __launch_bounds__(256, 3) void gemm1_kernel(
    const f16* __restrict__ xb,
    const float* __restrict__ gate_w, const float* __restrict__ up_w,
    const float* __restrict__ sgw, const float* __restrict__ suw,
    const int* __restrict__ row_token,
    const int* __restrict__ tile_expert, const int* __restrict__ tile_row0,
    const int* __restrict__ ntiles, f16* __restrict__ hbuf) {
  // XCD-aware swizzle: grid 192*32 = 6144 = 8*768 consecutive per XCD
  int d = blockIdx.y * gridDim.x + blockIdx.x;
  int l = (d & 7) * 768 + (d >> 3);
  int bx = l % MAX_TILES;
  int n0 = (l / MAX_TILES) * 64;
  if (bx >= ntiles[0]) return;
  int e = tile_expert[bx];
  int row0 = tile_row0[bx];
  const float* wg = (e < N_EXP) ? gate_w + (size_t)e * H_DIM * I_DIM : sgw;
  const float* wu = (e < N_EXP) ? up_w   + (size_t)e * H_DIM * I_DIM : suw;

  __shared__ __align__(16) f16 smem[2 * BM * BK + 2 * 64 * LDB];
  f16* A0 = smem;                 // [128][64] linear (gload_lds dest)
  f16* A1 = smem + BM * BK;
  f16 (*Bg)[LDB] = (f16(*)[LDB])(smem + 2 * BM * BK);
  f16 (*Bu)[LDB] = (f16(*)[LDB])(smem + 2 * BM * BK + 64 * LDB);
  f16 (*Ct)[LDB] = (f16(*)[LDB])smem;   // epilogue reuse

  int tid = threadIdx.x;
  int lane = tid & 63, wid = tid >> 6;
  int wm = wid >> 1, wn = wid & 1;
  int lr = lane & 15, lk = (lane >> 4) * 8;
  int nq = tid & 31, kr = tid >> 5;

  // A: per-lane source with column pre-swizzle keyed on LOCAL row (m173):
  // LDS[arow][c8] <- xb[tok][k0 + (c8/8 ^ arow&7)*8]; frag read mirrors XOR.
  const f16* abase[4];
#pragma unroll
  for (int it = 0; it < 4; ++it) {
    int idx = tid + it * 256;
    int arow = idx >> 3;
    int atok = row_token[row0 + arow];
    abase[it] = xb + (size_t)atok * H_DIM + ((((idx & 7)) ^ (arow & 7)) << 3);
  }
  const float* wgp = wg + (size_t)(8 * kr) * I_DIM + n0 + 2 * nq;
  const float* wup = wu + (size_t)(8 * kr) * I_DIM + n0 + 2 * nq;

  f32x4 accg[4][2], accu[4][2];
#pragma unroll
  for (int m = 0; m < 4; ++m)
#pragma unroll
    for (int n = 0; n < 2; ++n) { accg[m][n] = (f32x4)0.f; accu[m][n] = (f32x4)0.f; }

  // prologue: A tile 0 async; B tile 0 to regs
#pragma unroll
  for (int it = 0; it < 4; ++it)
    glds16(abase[it], A0 + (tid + it * 256) * 8);
  Bf2 pg = fetch_b2(wgp, I_DIM);
  Bf2 pu = fetch_b2(wup, I_DIM);

  for (int ks = 0; ks < H_DIM / BK; ++ks) {
    write_b2(pg, Bg, nq, kr);
    write_b2(pu, Bu, nq, kr);
    if (ks + 1 < H_DIM / BK) {
      int k0n = (ks + 1) * BK;
      f16* ad = ((ks + 1) & 1) ? A1 : A0;
#pragma unroll
      for (int it = 0; it < 4; ++it)
        glds16(abase[it] + k0n, ad + (tid + it * 256) * 8);
      pg = fetch_b2(wgp + (size_t)k0n * I_DIM, I_DIM);
      pu = fetch_b2(wup + (size_t)k0n * I_DIM, I_DIM);
    }
    __syncthreads();
    const f16* As = (ks & 1) ? A1 : A0;
#pragma unroll
    for (int kk = 0; kk < BK; kk += 32) {
      f16x8 a[4], bg[2], bu[2];
#pragma unroll
      for (int m = 0; m < 4; ++m) {
        int ar = wm * 64 + m * 16 + lr;
        int ko = (kk + lk) ^ ((ar & 7) << 3);
        a[m] = *(const f16x8*)(As + ar * BK + ko);
      }
#pragma unroll
      for (int n = 0; n < 2; ++n) {
        int rowb = wn * 32 + n * 16 + lr;
        int ko = rswz1(rowb, kk + lk);
        bg[n] = *(const f16x8*)&Bg[rowb][ko];
        bu[n] = *(const f16x8*)&Bu[rowb][ko];
      }
#pragma unroll
      for (int m = 0; m < 4; ++m)
#pragma unroll
        for (int n = 0; n < 2; ++n) {
          accg[m][n] = __builtin_amdgcn_mfma_f32_16x16x32_f16(a[m], bg[n], accg[m][n], 0, 0, 0);
          accu[m][n] = __builtin_amdgcn_mfma_f32_16x16x32_f16(a[m], bu[n], accu[m][n], 0, 0, 0);
        }
    }
    __syncthreads();
  }
  // epilogue: SwiGLU -> LDS bounce -> coalesced f16x8 stores (hbuf LINEAR)
#pragma unroll
  for (int m = 0; m < 4; ++m)
#pragma unroll
    for (int n = 0; n < 2; ++n)
#pragma unroll
      for (int j = 0; j < 4; ++j) {
        float g = accg[m][n][j], u = accu[m][n][j];
        float hv = g / (1.f + __expf(-g)) * u;
        Ct[wm * 64 + m * 16 + (lane >> 4) * 4 + j][wn * 32 + n * 16 + lr] = (f16)hv;
      }
  __syncthreads();
#pragma unroll
  for (int it = 0; it < 4; ++it) {
    int idx = tid + it * 256;
    int r = idx >> 3, g8 = (idx & 7) * 8;
    *(f16x8*)(hbuf + (size_t)(row0 + r) * I_DIM + n0 + g8) = *(const f16x8*)&Ct[r][g8];
  }
}

// ---------------------------------------------------------------- GEMM2 ---
// 128x64 tile of down. A (hbuf) via global_load_lds dbuf source-swizzled;
// B reg-staged. Output: per-row ybuf f16 (no atomics).
__global__ __launch_bounds__(256, 3) void gemm2_kernel(
    const f16* __restrict__ hbuf,
    const float* __restrict__ down_w, const float* __restrict__ sdw,
    const int* __restrict__ tile_expert, const int* __restrict__ tile_row0,
    const int* __restrict__ ntiles, f16* __restrict__ ybuf) {
  // grid 192*16 = 3072 = 8*384 consecutive per XCD
  int d = blockIdx.y * gridDim.x + blockIdx.x;
  int l = (d & 7) * 384 + (d >> 3);
  int bx = l % MAX_TILES;
  int n0 = (l / MAX_TILES) * 64;
  if (bx >= ntiles[0]) return;
  int e = tile_expert[bx];
  int row0 = tile_row0[bx];
  const float* wd = (e < N_EXP) ? down_w + (size_t)e * I_DIM * H_DIM : sdw;

  __shared__ __align__(16) f16 smem[2 * BM * BK + 64 * LDB];
  f16* A0 = smem;
  f16* A1 = smem + BM * BK;
  f16 (*Bd)[LDB] = (f16(*)[LDB])(smem + 2 * BM * BK);
  f16 (*Ct)[LDB] = (f16(*)[LDB])smem;

  int tid = threadIdx.x;
  int lane = tid & 63, wid = tid >> 6;
  int wm = wid >> 1, wn = wid & 1;
  int lr = lane & 15, lk = (lane >> 4) * 8;
  int nq = tid & 31, kr = tid >> 5;

  const f16* abase[4];
#pragma unroll
  for (int it = 0; it < 4; ++it) {
    int idx = tid + it * 256;
    int arow = idx >> 3;
    abase[it] = hbuf + (size_t)(row0 + arow) * I_DIM + ((((idx & 7)) ^ (arow & 7)) << 3);
  }
  const float* wdp = wd + (size_t)(8 * kr) * H_DIM + n0 + 2 * nq;

  f32x4 acc[4][2];
#pragma unroll
  for (int m = 0; m < 4; ++m)
#pragma unroll
    for (int n = 0; n < 2; ++n) acc[m][n] = (f32x4)0.f;

#pragma unroll
  for (int it = 0; it < 4; ++it)
    glds16(abase[it], A0 + (tid + it * 256) * 8);
  Bf2 pd = fetch_b2(wdp, H_DIM);

  for (int ks = 0; ks < I_DIM / BK; ++ks) {
    write_b2(pd, Bd, nq, kr);
    if (ks + 1 < I_DIM / BK) {
      int k0n = (ks + 1) * BK;
      f16* ad = ((ks + 1) & 1) ? A1 : A0;
#pragma unroll
      for (int it = 0; it < 4; ++it)
        glds16(abase[it] + k0n, ad + (tid + it * 256) * 8);
      pd = fetch_b2(wdp + (size_t)k0n * H_DIM, H_DIM);
    }
    __syncthreads();
    const f16* As = (ks & 1) ? A1 : A0;
#pragma unroll
    for (int kk = 0; kk < BK; kk += 32) {
      f16x8 a[4], bd[2];
#pragma unroll
      for (int m = 0; m < 4; ++m) {
        int ar = wm * 64 + m * 16 + lr;
        int ko = (kk + lk) ^ ((ar & 7) << 3);
        a[m] = *(const f16x8*)(As + ar * BK + ko);
      }
#pragma unroll
      for (int n = 0; n < 2; ++n) {
        int rowb = wn * 32 + n * 16 + lr;
        bd[n] = *(const f16x8*)&Bd[rowb][rswz1(rowb, kk + lk)];
      }
#pragma unroll
      for (int m = 0; m < 4; ++m)
#pragma unroll
        for (int n = 0; n < 2; ++n)
          acc[m][n] = __builtin_amdgcn_mfma_f32_16x16x32_f16(a[m], bd[n], acc[m][n], 0, 0, 0);
    }
    __syncthreads();
  }
  // epilogue -> ybuf f16 (linear), LDS bounce for coalescing
#pragma unroll
  for (int m = 0; m < 4; ++m)
#pragma unroll
    for (int n = 0; n < 2; ++n)
#pragma unroll
      for (int j = 0; j < 4; ++j)
        Ct[wm * 64 + m * 16 + (lane >> 4) * 4 + j][wn * 32 + n * 16 + lr] =
            (f16)acc[m][n][j];
  __syncthreads();
#pragma unroll
  for (int it = 0; it < 4; ++it) {
    int idx = tid + it * 256;
    int r = idx >> 3, g8 = (idx & 7) * 8;
    *(f16x8*)(ybuf + (size_t)(row0 + r) * H_DIM + n0 + g8) = *(const f16x8*)&Ct[r][g8];
  }
}

// --------------------------------------------------------------- gather ---
// out[t] = ybuf[t] (shared) + sum_k w[t,k] * ybuf[slot_of[t,k]]
__global__ void gather_kernel(const f16* __restrict__ ybuf,
                              const int* __restrict__ slot_of,
                              const float* __restrict__ weight_sel,
                              float* __restrict__ out) {
  int gid = blockIdx.x * blockDim.x + threadIdx.x;   // T*128
  int t = gid >> 7, s8 = (gid & 127) * 8;
  f16x8 ysh = *(const f16x8*)(ybuf + (size_t)t * H_DIM + s8);
  float a[8];
#pragma unroll
  for (int j = 0; j < 8; ++j) a[j] = (float)ysh[j];
#pragma unroll
  for (int k = 0; k < 4; ++k) {
    int sl = slot_of[t * 4 + k];
    float w = weight_sel[t * 4 + k];
    f16x8 v = *(const f16x8*)(ybuf + (size_t)sl * H_DIM + s8);
#pragma unroll
    for (int j = 0; j < 8; ++j) a[j] += w * (float)v[j];
  }
  float4 o0 = { a[0], a[1], a[2], a[3] };
  float4 o1 = { a[4], a[5], a[6], a[7] };
  *(float4*)(out + (size_t)t * H_DIM + s8) = o0;
  *(float4*)(out + (size_t)t * H_DIM + s8 + 4) = o1;
}

// ------------------------------------------------------------- launcher ---
extern "C" void kernel_launch(void* const* d_in, const int* in_sizes, int n_in,
                              void* d_out, int out_size, void* d_ws, size_t ws_size,
                              hipStream_t stream) {
  const float* x        = (const float*)d_in[0];
  const float* router_w = (const float*)d_in[1];
  const float* gate_w   = (const float*)d_in[2];
  const float* up_w     = (const float*)d_in[3];
  const float* down_w   = (const float*)d_in[4];
  const float* sgw      = (const float*)d_in[5];
  const float* suw      = (const float*)d_in[6];
  const float* sdw      = (const float*)d_in[7];
  float* out = (float*)d_out;

  char* w = (char*)d_ws;
  f16*   xb         = (f16*)w;   w += (size_t)T_TOK * H_DIM * 2;
  int*   expert_sel = (int*)w;   w += (size_t)TKTOT * 4;
  float* weight_sel = (float*)w; w += (size_t)TKTOT * 4;
  int*   slot_of    = (int*)w;   w += (size_t)TKTOT * 4;
  int*   counts     = (int*)w;   w += 256;
  int*   cursor     = (int*)w;   w += 256;
  int*   tile_exp   = (int*)w;   w += MAX_TILES * 4;
  int*   tile_row0  = (int*)w;   w += MAX_TILES * 4;
  int*   ntiles     = (int*)w;   w += 256;
  int*   row_token  = (int*)w;   w += (size_t)ROWS_MAX * 4;
  f16*   hbuf       = (f16*)w;   w += (size_t)ROWS_MAX * I_DIM * 2;
  f16*   ybuf       = (f16*)w;   w += (size_t)ROWS_MAX * H_DIM * 2;
  if ((size_t)(w - (char*)d_ws) > ws_size) return;  // ws too small: fail loud

  prep_kernel<<<(T_TOK * H_DIM / 4) / 256, 256, 0, stream>>>(x, xb, row_token, counts);
  router_kernel<<<T_TOK / 4, 256, 0, stream>>>(x, router_w, expert_sel, weight_sel, counts);
  scan_kernel<<<1, 64, 0, stream>>>(counts, cursor, tile_exp, tile_row0, ntiles);
  scatter_kernel<<<TKTOT / 256, 256, 0, stream>>>(expert_sel, weight_sel, cursor, row_token, slot_of);
  gemm1_kernel<<<dim3(MAX_TILES, I_DIM / 64), 256, 0, stream>>>(
      xb, gate_w, up_w, sgw, suw, row_token, tile_exp, tile_row0, ntiles, hbuf);
  gemm2_kernel<<<dim3(MAX_TILES, H_DIM / 64), 256, 0, stream>>>(
      hbuf, down_w, sdw, tile_exp, tile_row0, ntiles, ybuf);
  gather_kernel<<<(T_TOK * (H_DIM / 8)) / 256, 256, 0, stream>>>(
      ybuf, slot_of, weight_sel, out);
}

// Round 8
// 653.012 us; speedup vs baseline: 1.1418x; 1.1418x over previous
//
#include <hip/hip_runtime.h>
#include <hip/hip_bf16.h>

// Problem constants (reference: T,H,I,E,K = 4096,1024,2048,32,4)
#define T_TOK 4096
#define H_DIM 1024
#define I_DIM 2048
#define N_EXP 32
#define TOPK  4
#define TKTOT (T_TOK * TOPK)      // 16384 expert-row slots
#define ROWS_MAX 24576            // 4096 shared rows + <=20480 padded expert rows
#define MAX_TILES 192             // 32 shared tiles + <=159 expert tiles
#define BM 128
#define BK 64
#define LDB 72                    // BK + 8 f16 pad -> 144 B rows (16B-aligned)

typedef _Float16 f16;
typedef __attribute__((ext_vector_type(2))) f16  f16x2;
typedef __attribute__((ext_vector_type(4))) f16  f16x4;
typedef __attribute__((ext_vector_type(8))) f16  f16x8;
typedef __attribute__((ext_vector_type(4))) float f32x4;

// async global->LDS, 16B per lane; LDS dest is wave-uniform base + lane*16
__device__ __forceinline__ void glds16(const f16* g, f16* l) {
  __builtin_amdgcn_global_load_lds(
      (const __attribute__((address_space(1))) void*)g,
      (__attribute__((address_space(3))) void*)l, 16, 0, 0);
}
__device__ __forceinline__ void sfence() { __builtin_amdgcn_sched_barrier(0); }
// pre-MFMA barrier: LDS writes visible; global loads stay in flight (no vmcnt!)
__device__ __forceinline__ void bar_pre() {
  sfence();
  asm volatile("s_waitcnt lgkmcnt(0)" ::: "memory");
  sfence();
  __builtin_amdgcn_s_barrier();
  sfence();
}
// post-MFMA barrier: protect single-buffered B LDS from next iter's writes
__device__ __forceinline__ void bar_post() {
  sfence();
  __builtin_amdgcn_s_barrier();
  sfence();
}

// ---------------------------------------------------------------- prep ----
__global__ void prep_kernel(const float* __restrict__ x, f16* __restrict__ xb,
                            int* __restrict__ row_token,
                            int* __restrict__ counts) {
  int gid = blockIdx.x * blockDim.x + threadIdx.x;   // 0 .. T*H/4-1
  float4 v = *(const float4*)(x + (size_t)gid * 4);
  f16x4 hv = { (f16)v.x, (f16)v.y, (f16)v.z, (f16)v.w };
  *(f16x4*)(xb + (size_t)gid * 4) = hv;
  if (gid < ROWS_MAX) row_token[gid] = (gid < T_TOK) ? gid : 0;
  if (gid < N_EXP) counts[gid] = 0;
}

// -------------------------------------------------------------- router ----
__global__ void router_kernel(const float* __restrict__ x,
                              const float* __restrict__ rw,
                              int* __restrict__ expert_sel,
                              float* __restrict__ weight_sel,
                              int* __restrict__ counts) {
  int wid = threadIdx.x >> 6, lane = threadIdx.x & 63;
  int t = blockIdx.x * 4 + wid;
  float xr[16];
#pragma unroll
  for (int j = 0; j < 16; ++j) xr[j] = x[(size_t)t * H_DIM + lane + j * 64];
  float l[32];
#pragma unroll
  for (int e = 0; e < 32; ++e) {
    float p = 0.f;
#pragma unroll
    for (int j = 0; j < 16; ++j) p += xr[j] * rw[(size_t)e * H_DIM + lane + j * 64];
#pragma unroll
    for (int off = 32; off; off >>= 1) p += __shfl_xor(p, off, 64);
    l[e] = p;
  }
  if (lane == 0) {
    unsigned used = 0;
    int sel[4]; float lv[4];
#pragma unroll
    for (int k = 0; k < 4; ++k) {
      float bv = -3.4e38f; int bi = 0;
#pragma unroll
      for (int e = 0; e < 32; ++e) {
        bool better = (((used >> e) & 1u) == 0u) && (l[e] > bv);
        bv = better ? l[e] : bv;
        bi = better ? e : bi;
      }
      used |= 1u << bi; sel[k] = bi; lv[k] = bv;
    }
    float m = lv[0];
    float p0 = __expf(lv[0] - m), p1 = __expf(lv[1] - m);
    float p2 = __expf(lv[2] - m), p3 = __expf(lv[3] - m);
    float s = p0 + p1 + p2 + p3;
    float wv[4] = { p0 / s, p1 / s, p2 / s, p3 / s };
#pragma unroll
    for (int k = 0; k < 4; ++k) {
      expert_sel[t * 4 + k] = sel[k];
      weight_sel[t * 4 + k] = wv[k];
      atomicAdd(&counts[sel[k]], 1);
    }
  }
}

// ---------------------------------------------------------------- scan ----
__global__ void scan_kernel(const int* __restrict__ counts, int* __restrict__ cursor,
                            int* __restrict__ tile_expert, int* __restrict__ tile_row0,
                            int* __restrict__ ntiles) {
  if (threadIdx.x != 0 || blockIdx.x != 0) return;
  int nt = 0;
  for (int i = 0; i < T_TOK / BM; ++i) { tile_expert[nt] = N_EXP; tile_row0[nt] = i * BM; ++nt; }
  int pos = T_TOK;
  for (int e = 0; e < N_EXP; ++e) {
    cursor[e] = pos;
    int c = counts[e];
    int nte = (c + BM - 1) / BM;
    for (int i = 0; i < nte; ++i) { tile_expert[nt] = e; tile_row0[nt] = pos + i * BM; ++nt; }
    pos += nte * BM;
  }
  ntiles[0] = nt;
}

// ------------------------------------------------------------- scatter ----
__global__ void scatter_kernel(const int* __restrict__ expert_sel,
                               int* __restrict__ cursor,
                               int* __restrict__ row_token,
                               int* __restrict__ slot_of) {
  int i = blockIdx.x * blockDim.x + threadIdx.x;
  if (i >= TKTOT) return;
  int e = expert_sel[i];
  int pos = atomicAdd(&cursor[e], 1);
  row_token[pos] = i >> 2;
  slot_of[i] = pos;
}

// ------------------------- B staging helpers (fetch regs / cvt+write LDS) --
// gemm1 (BN=64): thread covers 2 n x 8 k via float2 rows.
struct Bf2 { float2 g[8]; };
__device__ __forceinline__ Bf2 fetch_b2(const float* __restrict__ src, size_t ldn) {
  Bf2 r;
#pragma unroll
  for (int j = 0; j < 8; ++j) r.g[j] = *(const float2*)(src + (size_t)j * ldn);
  return r;
}
__device__ __forceinline__ void write_b2(const Bf2& b,
                                         f16 (*__restrict__ Bs)[LDB], int nq, int kr) {
  const float* ga = (const float*)b.g;        // ga[j*2 + comp]
  int ks = (8 * kr) ^ ((nq & 7) << 3);        // swizzled 16B slot (f16 units)
#pragma unroll
  for (int i = 0; i < 2; ++i) {
    union { f16x2 p[4]; f16x8 v; } u;
#pragma unroll
    for (int j = 0; j < 4; ++j)
      u.p[j] = __builtin_bit_cast(
          f16x2, __builtin_amdgcn_cvt_pkrtz(ga[(2 * j) * 2 + i],
                                            ga[(2 * j + 1) * 2 + i]));
    *(f16x8*)&Bs[2 * nq + i][ks] = u.v;
  }
}
__device__ __forceinline__ int rswz1(int row, int kf16) {
  return kf16 ^ (((row >> 1) & 7) << 3);
}

// gemm2 (BN=128): thread covers 4 n x 8 k via float4 rows.
struct Bf4 { float4 g[8]; };
__device__ __forceinline__ Bf4 fetch_b4(const float* __restrict__ src, size_t ldn) {
  Bf4 r;
#pragma unroll
  for (int j = 0; j < 8; ++j) r.g[j] = *(const float4*)(src + (size_t)j * ldn);
  return r;
}
__device__ __forceinline__ void write_b4(const Bf4& b,
                                         f16 (*__restrict__ Bs)[LDB], int nq, int kr) {
  const float* ga = (const float*)b.g;        // ga[j*4 + comp]
  int ks = (8 * kr) ^ ((nq & 7) << 3);
#pragma unroll
  for (int i = 0; i < 4; ++i) {
    union { f16x2 p[4]; f16x8 v; } u;
#pragma unroll
    for (int j = 0; j < 4; ++j)
      u.p[j] = __builtin_bit_cast(
          f16x2, __builtin_amdgcn_cvt_pkrtz(ga[(2 * j) * 4 + i],
                                            ga[(2 * j + 1) * 4 + i]));
    *(f16x8*)&Bs[4 * nq + i][ks] = u.v;
  }
}
__device__ __forceinline__ int rswz2(int row, int kf16) {
  return kf16 ^ (((row >> 2) & 7) << 3);
}

// ---------------------------------------------------------------- GEMM1 ---
// 128x64 tile of gate AND up. A via global_load_lds (dbuf, source-swizzled),
// B reg-staged fp32->f16. Raw-barrier pipelined k-loop: next tile's loads
// stay in flight across the barriers (no vmcnt(0) drain).
__global__ __launch_bounds__(256, 3) void gemm1_kernel(
    const f16* __restrict__ xb,
    const float* __restrict__ gate_w, const float* __restrict__ up_w,
    const float* __restrict__ sgw, const float* __restrict__ suw,
    const int* __restrict__ row_token,
    const int* __restrict__ tile_expert, const int* __restrict__ tile_row0,
    const int* __restrict__ ntiles, f16* __restrict__ hbuf) {
  // XCD-aware swizzle: grid 192*32 = 6144 = 8*768 consecutive per XCD
  int d = blockIdx.y * gridDim.x + blockIdx.x;
  int l = (d & 7) * 768 + (d >> 3);
  int bx = l % MAX_TILES;
  int n0 = (l / MAX_TILES) * 64;
  if (bx >= ntiles[0]) return;
  int e = tile_expert[bx];
  int row0 = tile_row0[bx];
  const float* wg = (e < N_EXP) ? gate_w + (size_t)e * H_DIM * I_DIM : sgw;
  const float* wu = (e < N_EXP) ? up_w   + (size_t)e * H_DIM * I_DIM : suw;

  __shared__ __align__(16) f16 smem[2 * BM * BK + 2 * 64 * LDB];
  f16* A0 = smem;                 // [128][64] linear (gload_lds dest)
  f16* A1 = smem + BM * BK;
  f16 (*Bg)[LDB] = (f16(*)[LDB])(smem + 2 * BM * BK);
  f16 (*Bu)[LDB] = (f16(*)[LDB])(smem + 2 * BM * BK + 64 * LDB);
  f16 (*Ct)[LDB] = (f16(*)[LDB])smem;   // epilogue reuse

  int tid = threadIdx.x;
  int lane = tid & 63, wid = tid >> 6;
  int wm = wid >> 1, wn = wid & 1;
  int lr = lane & 15, lk = (lane >> 4) * 8;
  int nq = tid & 31, kr = tid >> 5;

  // A: per-lane source with column pre-swizzle keyed on LOCAL row (m173)
  const f16* abase[4];
#pragma unroll
  for (int it = 0; it < 4; ++it) {
    int idx = tid + it * 256;
    int arow = idx >> 3;
    int atok = row_token[row0 + arow];
    abase[it] = xb + (size_t)atok * H_DIM + ((((idx & 7)) ^ (arow & 7)) << 3);
  }
  const float* wgp = wg + (size_t)(8 * kr) * I_DIM + n0 + 2 * nq;
  const float* wup = wu + (size_t)(8 * kr) * I_DIM + n0 + 2 * nq;

  f32x4 accg[4][2], accu[4][2];
#pragma unroll
  for (int m = 0; m < 4; ++m)
#pragma unroll
    for (int n = 0; n < 2; ++n) { accg[m][n] = (f32x4)0.f; accu[m][n] = (f32x4)0.f; }

  // prologue: A tile 0 async (issued BEFORE B so B's reg-wait drains A too)
  sfence();
#pragma unroll
  for (int it = 0; it < 4; ++it)
    glds16(abase[it], A0 + (tid + it * 256) * 8);
  sfence();
  Bf2 pg = fetch_b2(wgp, I_DIM);
  Bf2 pu = fetch_b2(wup, I_DIM);
  sfence();

  const int NK = H_DIM / BK;
  for (int ks = 0; ks < NK; ++ks) {
    // write phase: compiler's wait for pg/pu regs also drains A(ks) glds
    write_b2(pg, Bg, nq, kr);
    write_b2(pu, Bu, nq, kr);
    if (ks + 1 < NK) {
      int k0n = (ks + 1) * BK;
      f16* ad = ((ks + 1) & 1) ? A1 : A0;
      sfence();
#pragma unroll
      for (int it = 0; it < 4; ++it)
        glds16(abase[it] + k0n, ad + (tid + it * 256) * 8);
      sfence();
      pg = fetch_b2(wgp + (size_t)k0n * I_DIM, I_DIM);
      pu = fetch_b2(wup + (size_t)k0n * I_DIM, I_DIM);
      sfence();
    }
    bar_pre();   // lgkmcnt(0) + s_barrier; next-tile loads stay in flight
    const f16* As = (ks & 1) ? A1 : A0;
    __builtin_amdgcn_s_setprio(1);
#pragma unroll
    for (int kk = 0; kk < BK; kk += 32) {
      f16x8 a[4], bg[2], bu[2];
#pragma unroll
      for (int m = 0; m < 4; ++m) {
        int ar = wm * 64 + m * 16 + lr;
        int ko = (kk + lk) ^ ((ar & 7) << 3);
        a[m] = *(const f16x8*)(As + ar * BK + ko);
      }
#pragma unroll
      for (int n = 0; n < 2; ++n) {
        int rowb = wn * 32 + n * 16 + lr;
        int ko = rswz1(rowb, kk + lk);
        bg[n] = *(const f16x8*)&Bg[rowb][ko];
        bu[n] = *(const f16x8*)&Bu[rowb][ko];
      }
#pragma unroll
      for (int m = 0; m < 4; ++m)
#pragma unroll
        for (int n = 0; n < 2; ++n) {
          accg[m][n] = __builtin_amdgcn_mfma_f32_16x16x32_f16(a[m], bg[n], accg[m][n], 0, 0, 0);
          accu[m][n] = __builtin_amdgcn_mfma_f32_16x16x32_f16(a[m], bu[n], accu[m][n], 0, 0, 0);
        }
    }
    __builtin_amdgcn_s_setprio(0);
    bar_post();  // all waves done reading Bg/Bu before next overwrite
  }
  // epilogue: SwiGLU -> LDS bounce -> coalesced f16x8 stores (hbuf LINEAR)
#pragma unroll
  for (int m = 0; m < 4; ++m)
#pragma unroll
    for (int n = 0; n < 2; ++n)
#pragma unroll
      for (int j = 0; j < 4; ++j) {
        float g = accg[m][n][j], u = accu[m][n][j];
        float hv = g / (1.f + __expf(-g)) * u;
        Ct[wm * 64 + m * 16 + (lane >> 4) * 4 + j][wn * 32 + n * 16 + lr] = (f16)hv;
      }
  __syncthreads();
#pragma unroll
  for (int it = 0; it < 4; ++it) {
    int idx = tid + it * 256;
    int r = idx >> 3, g8 = (idx & 7) * 8;
    *(f16x8*)(hbuf + (size_t)(row0 + r) * I_DIM + n0 + g8) = *(const f16x8*)&Ct[r][g8];
  }
}

// ---------------------------------------------------------------- GEMM2 ---
// 128x128 tile of down (BN=128: hbuf re-read 8x, not 16x). A via
// global_load_lds dbuf; B reg-staged. Output: per-row ybuf f16 (no atomics).
__global__ __launch_bounds__(256, 3) void gemm2_kernel(
    const f16* __restrict__ hbuf,
    const float* __restrict__ down_w, const float* __restrict__ sdw,
    const int* __restrict__ tile_expert, const int* __restrict__ tile_row0,
    const int* __restrict__ ntiles, f16* __restrict__ ybuf) {
  // grid 192*8 = 1536 = 8*192 consecutive per XCD
  int d = blockIdx.y * gridDim.x + blockIdx.x;
  int l = (d & 7) * 192 + (d >> 3);
  int bx = l % MAX_TILES;
  int n0 = (l / MAX_TILES) * 128;
  if (bx >= ntiles[0]) return;
  int e = tile_expert[bx];
  int row0 = tile_row0[bx];
  const float* wd = (e < N_EXP) ? down_w + (size_t)e * I_DIM * H_DIM : sdw;

  __shared__ __align__(16) f16 smem[2 * BM * BK + 128 * LDB];
  f16* A0 = smem;
  f16* A1 = smem + BM * BK;
  f16 (*Bd)[LDB] = (f16(*)[LDB])(smem + 2 * BM * BK);
  f16 (*Ct)[136] = (f16(*)[136])smem;   // 128*136*2 = 34.8KB <= 50.4KB

  int tid = threadIdx.x;
  int lane = tid & 63, wid = tid >> 6;
  int wm = wid >> 1, wn = wid & 1;
  int lr = lane & 15, lk = (lane >> 4) * 8;
  int nq = tid & 31, kr = tid >> 5;

  const f16* abase[4];
#pragma unroll
  for (int it = 0; it < 4; ++it) {
    int idx = tid + it * 256;
    int arow = idx >> 3;
    abase[it] = hbuf + (size_t)(row0 + arow) * I_DIM + ((((idx & 7)) ^ (arow & 7)) << 3);
  }
  const float* wdp = wd + (size_t)(8 * kr) * H_DIM + n0 + 4 * nq;

  f32x4 acc[4][4];
#pragma unroll
  for (int m = 0; m < 4; ++m)
#pragma unroll
    for (int n = 0; n < 4; ++n) acc[m][n] = (f32x4)0.f;

  sfence();
#pragma unroll
  for (int it = 0; it < 4; ++it)
    glds16(abase[it], A0 + (tid + it * 256) * 8);
  sfence();
  Bf4 pd = fetch_b4(wdp, H_DIM);
  sfence();

  const int NK = I_DIM / BK;
  for (int ks = 0; ks < NK; ++ks) {
    write_b4(pd, Bd, nq, kr);
    if (ks + 1 < NK) {
      int k0n = (ks + 1) * BK;
      f16* ad = ((ks + 1) & 1) ? A1 : A0;
      sfence();
#pragma unroll
      for (int it = 0; it < 4; ++it)
        glds16(abase[it] + k0n, ad + (tid + it * 256) * 8);
      sfence();
      pd = fetch_b4(wdp + (size_t)k0n * H_DIM, H_DIM);
      sfence();
    }
    bar_pre();
    const f16* As = (ks & 1) ? A1 : A0;
    __builtin_amdgcn_s_setprio(1);
#pragma unroll
    for (int kk = 0; kk < BK; kk += 32) {
      f16x8 a[4], bd[4];
#pragma unroll
      for (int m = 0; m < 4; ++m) {
        int ar = wm * 64 + m * 16 + lr;
        int ko = (kk + lk) ^ ((ar & 7) << 3);
        a[m] = *(const f16x8*)(As + ar * BK + ko);
      }
#pragma unroll
      for (int n = 0; n < 4; ++n) {
        int rowb = wn * 64 + n * 16 + lr;
        bd[n] = *(const f16x8*)&Bd[rowb][rswz2(rowb, kk + lk)];
      }
#pragma unroll
      for (int m = 0; m < 4; ++m)
#pragma unroll
        for (int n = 0; n < 4; ++n)
          acc[m][n] = __builtin_amdgcn_mfma_f32_16x16x32_f16(a[m], bd[n], acc[m][n], 0, 0, 0);
    }
    __builtin_amdgcn_s_setprio(0);
    bar_post();
  }
  // epilogue -> ybuf f16 (linear), LDS bounce for coalescing
#pragma unroll
  for (int m = 0; m < 4; ++m)
#pragma unroll
    for (int n = 0; n < 4; ++n)
#pragma unroll
      for (int j = 0; j < 4; ++j)
        Ct[wm * 64 + m * 16 + (lane >> 4) * 4 + j][wn * 64 + n * 16 + lr] =
            (f16)acc[m][n][j];
  __syncthreads();
#pragma unroll
  for (int it = 0; it < 8; ++it) {
    int idx = tid + it * 256;
    int r = idx >> 4, g8 = (idx & 15) * 8;
    *(f16x8*)(ybuf + (size_t)(row0 + r) * H_DIM + n0 + g8) = *(const f16x8*)&Ct[r][g8];
  }
}

// --------------------------------------------------------------- gather ---
// out[t] = ybuf[t] (shared) + sum_k w[t,k] * ybuf[slot_of[t,k]]
__global__ void gather_kernel(const f16* __restrict__ ybuf,
                              const int* __restrict__ slot_of,
                              const float* __restrict__ weight_sel,
                              float* __restrict__ out) {
  int gid = blockIdx.x * blockDim.x + threadIdx.x;   // T*128
  int t = gid >> 7, s8 = (gid & 127) * 8;
  f16x8 ysh = *(const f16x8*)(ybuf + (size_t)t * H_DIM + s8);
  float a[8];
#pragma unroll
  for (int j = 0; j < 8; ++j) a[j] = (float)ysh[j];
#pragma unroll
  for (int k = 0; k < 4; ++k) {
    int sl = slot_of[t * 4 + k];
    float w = weight_sel[t * 4 + k];
    f16x8 v = *(const f16x8*)(ybuf + (size_t)sl * H_DIM + s8);
#pragma unroll
    for (int j = 0; j < 8; ++j) a[j] += w * (float)v[j];
  }
  float4 o0 = { a[0], a[1], a[2], a[3] };
  float4 o1 = { a[4], a[5], a[6], a[7] };
  *(float4*)(out + (size_t)t * H_DIM + s8) = o0;
  *(float4*)(out + (size_t)t * H_DIM + s8 + 4) = o1;
}

// ------------------------------------------------------------- launcher ---
extern "C" void kernel_launch(void* const* d_in, const int* in_sizes, int n_in,
                              void* d_out, int out_size, void* d_ws, size_t ws_size,
                              hipStream_t stream) {
  const float* x        = (const float*)d_in[0];
  const float* router_w = (const float*)d_in[1];
  const float* gate_w   = (const float*)d_in[2];
  const float* up_w     = (const float*)d_in[3];
  const float* down_w   = (const float*)d_in[4];
  const float* sgw      = (const float*)d_in[5];
  const float* suw      = (const float*)d_in[6];
  const float* sdw      = (const float*)d_in[7];
  float* out = (float*)d_out;

  char* w = (char*)d_ws;
  f16*   xb         = (f16*)w;   w += (size_t)T_TOK * H_DIM * 2;
  int*   expert_sel = (int*)w;   w += (size_t)TKTOT * 4;
  float* weight_sel = (float*)w; w += (size_t)TKTOT * 4;
  int*   slot_of    = (int*)w;   w += (size_t)TKTOT * 4;
  int*   counts     = (int*)w;   w += 256;
  int*   cursor     = (int*)w;   w += 256;
  int*   tile_exp   = (int*)w;   w += MAX_TILES * 4;
  int*   tile_row0  = (int*)w;   w += MAX_TILES * 4;
  int*   ntiles     = (int*)w;   w += 256;
  int*   row_token  = (int*)w;   w += (size_t)ROWS_MAX * 4;
  f16*   hbuf       = (f16*)w;   w += (size_t)ROWS_MAX * I_DIM * 2;
  f16*   ybuf       = (f16*)w;   w += (size_t)ROWS_MAX * H_DIM * 2;
  if ((size_t)(w - (char*)d_ws) > ws_size) return;  // ws too small: fail loud

  prep_kernel<<<(T_TOK * H_DIM / 4) / 256, 256, 0, stream>>>(x, xb, row_token, counts);
  router_kernel<<<T_TOK / 4, 256, 0, stream>>>(x, router_w, expert_sel, weight_sel, counts);
  scan_kernel<<<1, 64, 0, stream>>>(counts, cursor, tile_exp, tile_row0, ntiles);
  scatter_kernel<<<TKTOT / 256, 256, 0, stream>>>(expert_sel, cursor, row_token, slot_of);
  gemm1_kernel<<<dim3(MAX_TILES, I_DIM / 64), 256, 0, stream>>>(
      xb, gate_w, up_w, sgw, suw, row_token, tile_exp, tile_row0, ntiles, hbuf);
  gemm2_kernel<<<dim3(MAX_TILES, H_DIM / 128), 256, 0, stream>>>(
      hbuf, down_w, sdw, tile_exp, tile_row0, ntiles, ybuf);
  gather_kernel<<<(T_TOK * (H_DIM / 8)) / 256, 256, 0, stream>>>(
      ybuf, slot_of, weight_sel, out);
}